// Round 9
// baseline (344.886 us; speedup 1.0000x reference)
//
#include <hip/hip_runtime.h>
#include <hip/hip_bf16.h>
#include <stdint.h>

typedef float  f32x4  __attribute__((ext_vector_type(4)));
typedef short  s16x8  __attribute__((ext_vector_type(8)));

#define GLOAD_LDS16(g, l)                                                          \
  __builtin_amdgcn_global_load_lds(                                               \
      (const __attribute__((address_space(1))) unsigned int*)(g),                 \
      (__attribute__((address_space(3))) unsigned int*)(l), 16, 0, 0)

#define WAITVM_(N) asm volatile("s_waitcnt vmcnt(" #N ")" ::: "memory")
#define WAITVM(N) WAITVM_(N)
#define WAITLGKM0 asm volatile("s_waitcnt lgkmcnt(0)" ::: "memory")

static __device__ __forceinline__ unsigned short f2bf(float f) {
  union { __hip_bfloat16 b; unsigned short s; } cv;
  cv.b = __float2bfloat16(f);          // RNE
  return cv.s;
}

static __device__ __forceinline__ int swz_e(int r) { return ((r & 3) ^ ((r >> 2) & 1)); }
static __device__ __forceinline__ int swz_byte(int r, int c) {
  return r * 64 + (((c ^ swz_e(r)) & 3) << 4);
}

// ---------------- A materialization: Amat[row][(k-1)*1024 + d] = bf16(T_k(x[row][d])) ----------------
__global__ __launch_bounds__(256) void agen(const float* __restrict__ x,
                                            short* __restrict__ amat) {
  const int g = blockIdx.x * 256 + threadIdx.x;   // 0 .. 1048575
  const int row = g >> 7;
  const int d0 = (g & 127) << 3;
  const float* xp = x + (size_t)row * 1024 + d0;
  f32x4 a = *(const f32x4*)xp, b = *(const f32x4*)(xp + 4);
  float p1[8], p2[8], x2[8];
  #pragma unroll
  for (int i = 0; i < 8; ++i) {
    float v = (i < 4) ? a[i] : b[i - 4];
    p1[i] = v; p2[i] = 1.f; x2[i] = v + v;
  }
  short* dst = amat + (size_t)row * 8192 + d0;
  #pragma unroll
  for (int k = 1; k <= 8; ++k) {
    union { unsigned short u[8]; s16x8 v; } o;
    #pragma unroll
    for (int i = 0; i < 8; ++i) o.u[i] = f2bf(p1[i]);
    *(s16x8*)(dst + (size_t)(k - 1) * 1024) = o.v;
    if (k < 8) {
      #pragma unroll
      for (int i = 0; i < 8; ++i) {
        float c = fmaf(x2[i], p1[i], -p2[i]);
        p2[i] = p1[i]; p1[i] = c;
      }
    }
  }
}

// ---------------- Wt2[col][(k-1)*1024 + d] = bf16(W[k][d][col]), k = 1..8 ----------------
__global__ __launch_bounds__(256) void transpose_w2(const float* __restrict__ w,
                                                    short* __restrict__ wt) {
  __shared__ unsigned int ldsT[64 * 33];
  const int t = threadIdx.x;
  const int bid = blockIdx.x;
  const int kk = bid >> 8;            // 0..7  (k = kk+1)
  const int db = (bid >> 4) & 15;
  const int cb = bid & 15;
  const int d0 = db * 64, c0 = cb * 64;
  const float* src = w + (size_t)(kk + 1) * 1048576 + (size_t)d0 * 1024 + c0;
  #pragma unroll
  for (int p = 0; p < 4; ++p) {
    int dl = p * 16 + (t >> 4);
    int c4 = (t & 15) * 4;
    f32x4 f = *(const f32x4*)(src + (size_t)dl * 1024 + c4);
    unsigned lo = (unsigned)f2bf(f.x) | ((unsigned)f2bf(f.y) << 16);
    unsigned hi = (unsigned)f2bf(f.z) | ((unsigned)f2bf(f.w) << 16);
    ldsT[dl * 33 + (t & 15) * 2]     = lo;
    ldsT[dl * 33 + (t & 15) * 2 + 1] = hi;
  }
  __syncthreads();
  const int col = t >> 2;
  const int dc  = t & 3;
  union { unsigned short u[8]; s16x8 v; } o0, o1;
  #pragma unroll
  for (int j = 0; j < 16; ++j) {
    int dl = dc * 16 + j;
    unsigned word = ldsT[dl * 33 + (col >> 1)];
    unsigned short e = (col & 1) ? (unsigned short)(word >> 16) : (unsigned short)(word & 0xffffu);
    if (j < 8) o0.u[j] = e; else o1.u[j - 8] = e;
  }
  short* dst = wt + (size_t)(c0 + col) * 8192 + (size_t)kk * 1024 + d0 + dc * 16;
  *(s16x8*)dst       = o0.v;
  *(s16x8*)(dst + 8) = o1.v;
}

// ---------------- legacy pre-pass (MID path): Wt[k-1][col][d] ----------------
__global__ __launch_bounds__(256) void transpose_w(const float* __restrict__ w,
                                                   short* __restrict__ wt) {
  __shared__ unsigned int ldsT[64 * 33];
  const int t = threadIdx.x;
  const int bid = blockIdx.x;
  const int kb = bid >> 8;
  const int db = (bid >> 4) & 15;
  const int cb = bid & 15;
  const int d0 = db * 64, c0 = cb * 64;
  const float* src = w + (size_t)(kb + 1) * 1048576 + (size_t)d0 * 1024 + c0;
  #pragma unroll
  for (int p = 0; p < 4; ++p) {
    int dl = p * 16 + (t >> 4);
    int c4 = (t & 15) * 4;
    f32x4 f = *(const f32x4*)(src + (size_t)dl * 1024 + c4);
    unsigned lo = (unsigned)f2bf(f.x) | ((unsigned)f2bf(f.y) << 16);
    unsigned hi = (unsigned)f2bf(f.z) | ((unsigned)f2bf(f.w) << 16);
    ldsT[dl * 33 + (t & 15) * 2]     = lo;
    ldsT[dl * 33 + (t & 15) * 2 + 1] = hi;
  }
  __syncthreads();
  const int col = t >> 2;
  const int dc  = t & 3;
  union { unsigned short u[8]; s16x8 v; } o0, o1;
  #pragma unroll
  for (int j = 0; j < 16; ++j) {
    int dl = dc * 16 + j;
    unsigned word = ldsT[dl * 33 + (col >> 1)];
    unsigned short e = (col & 1) ? (unsigned short)(word >> 16) : (unsigned short)(word & 0xffffu);
    if (j < 8) o0.u[j] = e; else o1.u[j - 8] = e;
  }
  short* dst = wt + ((size_t)(kb * 1024 + c0 + col) * 1024 + d0 + dc * 16);
  *(s16x8*)dst       = o0.v;
  *(s16x8*)(dst + 8) = o1.v;
}

// ---------------- bias[c] = sum_d W[0][d][c] ----------------
__global__ __launch_bounds__(256) void bias_k(const float* __restrict__ w,
                                              float* __restrict__ b) {
  __shared__ float red[256];
  const int t = threadIdx.x;
  const int col = blockIdx.x * 64 + (t & 63);
  const int seg = t >> 6;
  float s = 0.f;
  const float* p = w + (size_t)(seg * 256) * 1024 + col;
  for (int d = 0; d < 256; ++d) s += p[(size_t)d * 1024];
  red[t] = s;
  __syncthreads();
  if (t < 64) b[col] = red[t] + red[t + 64] + red[t + 128] + red[t + 192];
}

// ---------------- out init: out[r][c] = bias[c] (or 0) ----------------
__global__ __launch_bounds__(256) void init_out(const float* __restrict__ bias,
                                                float* __restrict__ out, int has_bias) {
  const size_t i = (size_t)blockIdx.x * 256 + threadIdx.x;
  const int c = (int)((i * 4) & 1023);
  f32x4 v = has_bias ? *(const f32x4*)(bias + c) : (f32x4){0.f, 0.f, 0.f, 0.f};
  *(f32x4*)(out + i * 4) = v;
}

// ---------------- FULL path: A-read-once phase-split GEMM ----------------
// block 64M x 1024N (full N!), split-K x4 (dq = K/2048 quarter), 8 waves (1x8),
// wave tile 64x128, BK=32. A is fetched EXACTLY ONCE from HBM (134 MB total).
// dq pinned per XCD-pair -> B quarter (4 MB) L2/L3-hot. LDS: A ring 2x4KB,
// B ring 2x64KB = 136 KB. Per tile: 2 phases x {ds_read frags || issue stage(t+1)
// -> barrier -> lgkm(0) -> 16 MFMA}; per-wave vmcnt(0) only at tile end
// (~1700 cyc cover vs ~300-600 cyc warm latency).
__global__ __launch_bounds__(512, 2) void gemm9(
    const short* __restrict__ amat, const short* __restrict__ wt2,
    float* __restrict__ out) {
  __shared__ __attribute__((aligned(16))) char lds[139264]; // A 2x4096 @0; B 2x65536 @8192

  const int tid = threadIdx.x, lane = tid & 63, wid = tid >> 6;
  const int bid = blockIdx.x;
  const int xcd = bid & 7;
  const int dq  = xcd >> 1;                       // K quarter, pinned per XCD-pair
  const int mb  = ((bid >> 3) << 1) | (xcd & 1);  // 0..127
  const int rowbase = mb * 64;
  const size_t kq = (size_t)dq * 2048;
  const int la = lane & 15, lg = lane >> 4;
  const int ela = (la & 3) ^ ((la >> 2) & 1);

  // fragment read offsets
  int aoff[4], boff[8];
  #pragma unroll
  for (int m = 0; m < 4; ++m)
    aoff[m] = ((m * 16 + la) << 6) + ((lg ^ ela) << 4);
  #pragma unroll
  for (int n = 0; n < 8; ++n)
    boff[n] = 8192 + ((wid * 128 + n * 16 + la) << 6) + ((lg ^ ela) << 4);

  // stage sources (pre-swizzled global chunk; LDS dest is linear base + lane*16)
  const int rr   = lane >> 2;
  const int gchk = ((lane & 3) ^ ((rr & 3) ^ ((rr >> 2) & 1))) * 8;  // shorts
  // A: waves 0..3 each stage 16 rows (1 gload)
  const short* asrc = amat + (size_t)(rowbase + wid * 16 + rr) * 8192 + kq + gchk;
  // B: each wave stages 8 col-groups of 16 cols (8 gloads)
  const short* bsrc = wt2 + (size_t)(wid * 128 + rr) * 8192 + kq + gchk;
  const int bstep = 16 * 8192;                     // shorts per 16-col group

  f32x4 acc[4][8];
  #pragma unroll
  for (int m = 0; m < 4; ++m)
    #pragma unroll
    for (int n = 0; n < 8; ++n) acc[m][n] = (f32x4){0.f, 0.f, 0.f, 0.f};

#define STAGE_A(T, PAR)                                                            \
  { if (wid < 4) GLOAD_LDS16(asrc + (T) * 32, lds + (PAR) * 4096 + wid * 1024); }
#define STAGE_B(T, PAR, J0, J1)                                                    \
  { _Pragma("unroll")                                                              \
    for (int j_ = (J0); j_ < (J1); ++j_)                                           \
      GLOAD_LDS16(bsrc + (size_t)j_ * bstep + (T) * 32,                            \
                  lds + 8192 + (PAR) * 65536 + (wid * 8 + j_) * 1024); }

  // prologue: tile 0 -> parity 0
  STAGE_A(0, 0);
  STAGE_B(0, 0, 0, 8);
  WAITVM(0);
  __builtin_amdgcn_sched_barrier(0);
  __builtin_amdgcn_s_barrier();
  __builtin_amdgcn_sched_barrier(0);

  #pragma unroll 1
  for (int t = 0; t < 64; ++t) {
    const int par = t & 1;
    const int ao = par * 4096, bo = par * 65536;
    s16x8 af[4], bf[4];

    // ---- phase 0: n = 0..3 ----
    #pragma unroll
    for (int m = 0; m < 4; ++m) af[m] = *(const s16x8*)(lds + ao + aoff[m]);
    #pragma unroll
    for (int n = 0; n < 4; ++n) bf[n] = *(const s16x8*)(lds + bo + boff[n]);
    if (t < 63) { STAGE_A(t + 1, par ^ 1); STAGE_B(t + 1, par ^ 1, 0, 4); }
    __builtin_amdgcn_s_barrier();
    WAITLGKM0;
    __builtin_amdgcn_sched_barrier(0);
    __builtin_amdgcn_s_setprio(1);
    #pragma unroll
    for (int n = 0; n < 4; ++n)
      #pragma unroll
      for (int m = 0; m < 4; ++m)
        acc[m][n] = __builtin_amdgcn_mfma_f32_16x16x32_bf16(af[m], bf[n], acc[m][n], 0, 0, 0);
    __builtin_amdgcn_s_setprio(0);
    __builtin_amdgcn_sched_barrier(0);
    __builtin_amdgcn_s_barrier();
    __builtin_amdgcn_sched_barrier(0);

    // ---- phase 1: n = 4..7 ----
    #pragma unroll
    for (int n = 0; n < 4; ++n) bf[n] = *(const s16x8*)(lds + bo + boff[4 + n]);
    if (t < 63) STAGE_B(t + 1, par ^ 1, 4, 8);
    __builtin_amdgcn_s_barrier();
    WAITLGKM0;
    __builtin_amdgcn_sched_barrier(0);
    __builtin_amdgcn_s_setprio(1);
    #pragma unroll
    for (int n = 0; n < 4; ++n)
      #pragma unroll
      for (int m = 0; m < 4; ++m)
        acc[m][4 + n] = __builtin_amdgcn_mfma_f32_16x16x32_bf16(af[m], bf[n], acc[m][4 + n], 0, 0, 0);
    __builtin_amdgcn_s_setprio(0);
    // tile boundary: all of tile t+1's loads landed (per-wave own counts)
    if (t < 63) { WAITVM(0); }
    __builtin_amdgcn_sched_barrier(0);
    __builtin_amdgcn_s_barrier();
    __builtin_amdgcn_sched_barrier(0);
  }
#undef STAGE_A
#undef STAGE_B

  // epilogue: out += acc (split-K x4 partial), hardware f32 atomics
  #pragma unroll
  for (int m = 0; m < 4; ++m) {
    const int r0 = rowbase + m * 16 + lg * 4;
    #pragma unroll
    for (int n = 0; n < 8; ++n) {
      const int c = wid * 128 + n * 16 + la;
      #pragma unroll
      for (int j = 0; j < 4; ++j)
        unsafeAtomicAdd(&out[(size_t)(r0 + j) * 1024 + c], acc[m][n][j]);
    }
  }
}

// ---------------- MID path / fallback: R7 fused kernel (unchanged, proven) ----------------
template <bool USE_WS>
__global__ __launch_bounds__(256, 2) void cheb_gemm(
    const float* __restrict__ x, const float* __restrict__ w,
    const short* __restrict__ wt, float* __restrict__ out) {
  __shared__ short Asm[2][4096];
  __shared__ short Bsm[3][8192];

  const int tid = threadIdx.x, lane = tid & 63, wid = tid >> 6;
  const int bid = blockIdx.x;
  const int xcd = bid & 7;
  const int mb  = bid >> 3;
  const int nb  = xcd >> 1, kb = xcd & 1;
  const int rowbase = mb * 128, colbase = nb * 256;
  const int kbase = kb * 512;
  const int wr = wid >> 1, wc = wid & 1;
  const int la = lane & 15, lg = lane >> 4;
  const int e_la = (la & 3) ^ ((la >> 2) & 1);
  const int abase = (wr * 64 + la) * 64 + ((lg ^ e_la) << 4);
  const int bbase = (wc * 128 + la) * 64 + ((lg ^ e_la) << 4);

  const int arow = tid & 127, h = tid >> 7;
  const int aw0 = swz_byte(arow, 2 * h), aw1 = swz_byte(arow, 2 * h + 1);
  const float* xrow = x + (size_t)(rowbase + arow) * 1024 + kbase + h * 16;

  float p1[16], p2[16];
  unsigned x2h[8];
  f32x4 xq[4];
  f32x4 acc[4][8];
  #pragma unroll
  for (int m = 0; m < 4; ++m)
    #pragma unroll
    for (int n = 0; n < 8; ++n) acc[m][n] = (f32x4){0.f, 0.f, 0.f, 0.f};

  if constexpr (USE_WS) {
    const int bcol0  = wid * 64 + (lane >> 2);
    const int goff   = ((lane & 3) ^ swz_e(lane >> 2)) * 8;
    const short* gptr = wt + (size_t)(colbase + bcol0) * 1024 + kbase + goff;

#define ISSUE_AT(PTR, WOFF)                                                        \
    { _Pragma("unroll")                                                            \
      for (int j_ = 0; j_ < 4; ++j_)                                               \
        GLOAD_LDS16((PTR) + j_ * 16384,                                            \
                    (char*)&Bsm[0][0] + (WOFF) + (wid * 4 + j_) * 1024); }

    #pragma unroll
    for (int q = 0; q < 4; ++q) xq[q] = *(const f32x4*)(xrow + q * 4);
    ISSUE_AT(gptr, 0);          gptr += 1048576;
    ISSUE_AT(gptr, 16384);      gptr += 1048576;
    {
      union { unsigned short u[8]; s16x8 v; } o0, o1;
      #pragma unroll
      for (int i = 0; i < 16; ++i) { p1[i] = xq[i >> 2][i & 3]; p2[i] = 1.f; }
      #pragma unroll
      for (int i = 0; i < 8; ++i) {
        union { unsigned u; _Float16 f[2]; } t2;
        t2.f[0] = (_Float16)(p1[2 * i] + p1[2 * i]);
        t2.f[1] = (_Float16)(p1[2 * i + 1] + p1[2 * i + 1]);
        x2h[i] = t2.u;
        o0.u[i] = f2bf(p1[i]); o1.u[i] = f2bf(p1[i + 8]);
      }
      *(s16x8*)((char*)&Asm[0][0] + aw0) = o0.v;
      *(s16x8*)((char*)&Asm[0][0] + aw1) = o1.v;
    }
    WAITLGKM0;
    WAITVM(4);
    __builtin_amdgcn_sched_barrier(0);
    __builtin_amdgcn_s_barrier();
    __builtin_amdgcn_sched_barrier(0);

    int wroff = 32768, rdoff = 0, ard = 0;

    #pragma unroll 1
    for (int t = 0; t < 128; ++t) {
      if ((t & 7) == 2 && t < 120) {
        const float* xs = xrow + ((t >> 3) + 1) * 32;
        #pragma unroll
        for (int q = 0; q < 4; ++q) xq[q] = *(const f32x4*)(xs + q * 4);
      }
      if (t + 2 < 128) {
        ISSUE_AT(gptr, wroff);
        gptr += ((t & 7) == 5) ? (32 - 7 * 1048576) : 1048576;
        wroff = (wroff == 32768) ? 0 : wroff + 16384;
      }
      if (t + 1 < 128) {
        const int rn = (t + 1) & 7;
        union { unsigned short u[8]; s16x8 v; } o0, o1;
        if (rn == 0) {
          #pragma unroll
          for (int i = 0; i < 16; ++i) { p1[i] = xq[i >> 2][i & 3]; p2[i] = 1.f; }
          #pragma unroll
          for (int i = 0; i < 8; ++i) {
            union { unsigned u; _Float16 f[2]; } t2;
            t2.f[0] = (_Float16)(p1[2 * i] + p1[2 * i]);
            t2.f[1] = (_Float16)(p1[2 * i + 1] + p1[2 * i + 1]);
            x2h[i] = t2.u;
            o0.u[i] = f2bf(p1[i]); o1.u[i] = f2bf(p1[i + 8]);
          }
        } else {
          #pragma unroll
          for (int i = 0; i < 16; ++i) {
            union { unsigned u; _Float16 f[2]; } t2; t2.u = x2h[i >> 1];
            float cur = fmaf((float)t2.f[i & 1], p1[i], -p2[i]);
            p2[i] = p1[i]; p1[i] = cur;
            unsigned short e = f2bf(cur);
            if (i < 8) o0.u[i] = e; else o1.u[i - 8] = e;
          }
        }
        *(s16x8*)((char*)&Asm[0][0] + (ard ^ 8192) + aw0) = o0.v;
        *(s16x8*)((char*)&Asm[0][0] + (ard ^ 8192) + aw1) = o1.v;
      }
      s16x8 af[4];
      #pragma unroll
      for (int m = 0; m < 4; ++m)
        af[m] = *(const s16x8*)((char*)&Asm[0][0] + ard + abase + m * 1024);
      #pragma unroll
      for (int n = 0; n < 8; ++n) {
        s16x8 bfr = *(const s16x8*)((char*)&Bsm[0][0] + rdoff + bbase + n * 1024);
        #pragma unroll
        for (int m = 0; m < 4; ++m)
          acc[m][n] = __builtin_amdgcn_mfma_f32_16x16x32_bf16(af[m], bfr, acc[m][n], 0, 0, 0);
      }
      WAITLGKM0;
      if (t < 126) { WAITVM(4); } else { WAITVM(0); }
      __builtin_amdgcn_sched_barrier(0);
      __builtin_amdgcn_s_barrier();
      __builtin_amdgcn_sched_barrier(0);
      rdoff = (rdoff == 32768) ? 0 : rdoff + 16384;
      ard ^= 8192;
    }
#undef ISSUE_AT
  } else {
    #pragma unroll 1
    for (int s = 0; s < 144; ++s) {
      const int r = s % 9, st = s / 9;
      const int d0 = kbase + st * 32;
      __syncthreads();
      { const int dd = tid & 31, cg = tid >> 5;
        const float* ws_ = w + (size_t)r * 1048576 + (size_t)(d0 + dd) * 1024 + colbase + cg * 4;
        #pragma unroll
        for (int p_ = 0; p_ < 8; ++p_) {
          f32x4 f_ = *(const f32x4*)(ws_ + p_ * 32);
          #pragma unroll
          for (int jj = 0; jj < 4; ++jj) {
            int col = cg * 4 + p_ * 32 + jj;
            int byt = col * 64 + ((dd & 7) << 1) + ((((dd >> 3) ^ swz_e(col)) & 3) << 4);
            *(unsigned short*)((char*)&Bsm[0][0] + byt) = f2bf(f_[jj]);
          } } }
      union { unsigned short u[8]; s16x8 v; } o0, o1;
      if (r == 0) {
        #pragma unroll
        for (int q = 0; q < 4; ++q) xq[q] = *(const f32x4*)(xrow + st * 32 + q * 4);
        #pragma unroll
        for (int i = 0; i < 16; ++i) { p1[i] = xq[i >> 2][i & 3]; p2[i] = 1.f; }
        #pragma unroll
        for (int i = 0; i < 8; ++i) {
          union { unsigned u; _Float16 f[2]; } t2;
          t2.f[0] = (_Float16)(p1[2 * i] + p1[2 * i]);
          t2.f[1] = (_Float16)(p1[2 * i + 1] + p1[2 * i + 1]);
          x2h[i] = t2.u;
          o0.u[i] = 0x3f80; o1.u[i] = 0x3f80;
        }
      } else if (r == 1) {
        #pragma unroll
        for (int i = 0; i < 8; ++i) { o0.u[i] = f2bf(p1[i]); o1.u[i] = f2bf(p1[i + 8]); }
      } else {
        #pragma unroll
        for (int i = 0; i < 16; ++i) {
          union { unsigned u; _Float16 f[2]; } t2; t2.u = x2h[i >> 1];
          float cur = fmaf((float)t2.f[i & 1], p1[i], -p2[i]);
          p2[i] = p1[i]; p1[i] = cur;
          if (i < 8) o0.u[i] = f2bf(cur); else o1.u[i - 8] = f2bf(cur);
        }
      }
      *(s16x8*)((char*)&Asm[0][0] + aw0) = o0.v;
      *(s16x8*)((char*)&Asm[0][0] + aw1) = o1.v;
      __syncthreads();
      s16x8 af[4];
      #pragma unroll
      for (int m = 0; m < 4; ++m)
        af[m] = *(const s16x8*)((char*)&Asm[0][0] + abase + m * 1024);
      #pragma unroll
      for (int n = 0; n < 8; ++n) {
        s16x8 bfr = *(const s16x8*)((char*)&Bsm[0][0] + bbase + n * 1024);
        #pragma unroll
        for (int m = 0; m < 4; ++m)
          acc[m][n] = __builtin_amdgcn_mfma_f32_16x16x32_bf16(af[m], bfr, acc[m][n], 0, 0, 0);
      }
    }
  }

  #pragma unroll
  for (int m = 0; m < 4; ++m) {
    const int r0 = rowbase + wr * 64 + m * 16 + lg * 4;
    #pragma unroll
    for (int n = 0; n < 8; ++n) {
      const int c = colbase + wc * 128 + n * 16 + la;
      #pragma unroll
      for (int j = 0; j < 4; ++j)
        unsafeAtomicAdd(&out[(size_t)(r0 + j) * 1024 + c], acc[m][n][j]);
    }
  }
}

extern "C" void kernel_launch(void* const* d_in, const int* in_sizes, int n_in,
                              void* d_out, int out_size, void* d_ws, size_t ws_size,
                              hipStream_t stream) {
  const float* x = (const float*)d_in[0];
  const float* w = (const float*)d_in[1];
  float* out = (float*)d_out;

  const size_t AMAT_BYTES = (size_t)8192 * 8192 * 2;   // 134 MiB
  const size_t WT2_BYTES  = (size_t)1024 * 8192 * 2;   // 16 MiB
  const size_t WT_BYTES   = (size_t)8 * 1024 * 1024 * 2;

  if (ws_size >= AMAT_BYTES + WT2_BYTES + 4096) {
    // FULL: materialize A (read once by GEMM), re-layout W, phase-split GEMM
    short* amat = (short*)d_ws;
    short* wt2  = (short*)((char*)d_ws + AMAT_BYTES);
    float* bias = (float*)((char*)d_ws + AMAT_BYTES + WT2_BYTES);
    agen<<<4096, 256, 0, stream>>>(x, amat);
    transpose_w2<<<2048, 256, 0, stream>>>(w, wt2);
    bias_k<<<16, 256, 0, stream>>>(w, bias);
    init_out<<<8192, 256, 0, stream>>>(bias, out, 1);
    gemm9<<<512, 512, 0, stream>>>(amat, wt2, out);
  } else if (ws_size >= WT_BYTES + 4096) {
    // MID: R7 fused kernel
    short* wt   = (short*)d_ws;
    float* bias = (float*)((char*)d_ws + WT_BYTES);
    transpose_w<<<2048, 256, 0, stream>>>(w, wt);
    bias_k<<<16, 256, 0, stream>>>(w, bias);
    init_out<<<8192, 256, 0, stream>>>(bias, out, 1);
    cheb_gemm<true><<<512, 256, 0, stream>>>(x, w, wt, out);
  } else {
    init_out<<<8192, 256, 0, stream>>>(nullptr, out, 0);
    cheb_gemm<false><<<512, 256, 0, stream>>>(x, w, nullptr, out);
  }
}

// Round 10
// 249.329 us; speedup vs baseline: 1.3833x; 1.3833x over previous
//
#include <hip/hip_runtime.h>
#include <hip/hip_bf16.h>
#include <stdint.h>

typedef float  f32x4  __attribute__((ext_vector_type(4)));
typedef short  s16x8  __attribute__((ext_vector_type(8)));

#define GLOAD_LDS16(g, l)                                                          \
  __builtin_amdgcn_global_load_lds(                                               \
      (const __attribute__((address_space(1))) unsigned int*)(g),                 \
      (__attribute__((address_space(3))) unsigned int*)(l), 16, 0, 0)

#define WAITVM_(N) asm volatile("s_waitcnt vmcnt(" #N ")" ::: "memory")
#define WAITVM(N) WAITVM_(N)
#define WAITLGKM0 asm volatile("s_waitcnt lgkmcnt(0)" ::: "memory")

static __device__ __forceinline__ unsigned short f2bf(float f) {
  union { __hip_bfloat16 b; unsigned short s; } cv;
  cv.b = __float2bfloat16(f);          // RNE
  return cv.s;
}

static __device__ __forceinline__ int swz_e(int r) { return ((r & 3) ^ ((r >> 2) & 1)); }
static __device__ __forceinline__ int swz_byte(int r, int c) {
  return r * 64 + (((c ^ swz_e(r)) & 3) << 4);
}

// ---------------- A materialization: Amat[row][(k-1)*1024 + d] = bf16(T_k(x[row][d])) ----------------
__global__ __launch_bounds__(256) void agen(const float* __restrict__ x,
                                            short* __restrict__ amat) {
  const int g = blockIdx.x * 256 + threadIdx.x;   // 0 .. 1048575
  const int row = g >> 7;
  const int d0 = (g & 127) << 3;
  const float* xp = x + (size_t)row * 1024 + d0;
  f32x4 a = *(const f32x4*)xp, b = *(const f32x4*)(xp + 4);
  float p1[8], p2[8], x2[8];
  #pragma unroll
  for (int i = 0; i < 8; ++i) {
    float v = (i < 4) ? a[i] : b[i - 4];
    p1[i] = v; p2[i] = 1.f; x2[i] = v + v;
  }
  short* dst = amat + (size_t)row * 8192 + d0;
  #pragma unroll
  for (int k = 1; k <= 8; ++k) {
    union { unsigned short u[8]; s16x8 v; } o;
    #pragma unroll
    for (int i = 0; i < 8; ++i) o.u[i] = f2bf(p1[i]);
    *(s16x8*)(dst + (size_t)(k - 1) * 1024) = o.v;
    if (k < 8) {
      #pragma unroll
      for (int i = 0; i < 8; ++i) {
        float c = fmaf(x2[i], p1[i], -p2[i]);
        p2[i] = p1[i]; p1[i] = c;
      }
    }
  }
}

// ---------------- Wt2[col][(k-1)*1024 + d] = bf16(W[k][d][col]), k = 1..8 ----------------
__global__ __launch_bounds__(256) void transpose_w2(const float* __restrict__ w,
                                                    short* __restrict__ wt) {
  __shared__ unsigned int ldsT[64 * 33];
  const int t = threadIdx.x;
  const int bid = blockIdx.x;
  const int kk = bid >> 8;            // 0..7  (k = kk+1)
  const int db = (bid >> 4) & 15;
  const int cb = bid & 15;
  const int d0 = db * 64, c0 = cb * 64;
  const float* src = w + (size_t)(kk + 1) * 1048576 + (size_t)d0 * 1024 + c0;
  #pragma unroll
  for (int p = 0; p < 4; ++p) {
    int dl = p * 16 + (t >> 4);
    int c4 = (t & 15) * 4;
    f32x4 f = *(const f32x4*)(src + (size_t)dl * 1024 + c4);
    unsigned lo = (unsigned)f2bf(f.x) | ((unsigned)f2bf(f.y) << 16);
    unsigned hi = (unsigned)f2bf(f.z) | ((unsigned)f2bf(f.w) << 16);
    ldsT[dl * 33 + (t & 15) * 2]     = lo;
    ldsT[dl * 33 + (t & 15) * 2 + 1] = hi;
  }
  __syncthreads();
  const int col = t >> 2;
  const int dc  = t & 3;
  union { unsigned short u[8]; s16x8 v; } o0, o1;
  #pragma unroll
  for (int j = 0; j < 16; ++j) {
    int dl = dc * 16 + j;
    unsigned word = ldsT[dl * 33 + (col >> 1)];
    unsigned short e = (col & 1) ? (unsigned short)(word >> 16) : (unsigned short)(word & 0xffffu);
    if (j < 8) o0.u[j] = e; else o1.u[j - 8] = e;
  }
  short* dst = wt + (size_t)(c0 + col) * 8192 + (size_t)kk * 1024 + d0 + dc * 16;
  *(s16x8*)dst       = o0.v;
  *(s16x8*)(dst + 8) = o1.v;
}

// ---------------- legacy pre-pass (MID path): Wt[k-1][col][d] ----------------
__global__ __launch_bounds__(256) void transpose_w(const float* __restrict__ w,
                                                   short* __restrict__ wt) {
  __shared__ unsigned int ldsT[64 * 33];
  const int t = threadIdx.x;
  const int bid = blockIdx.x;
  const int kb = bid >> 8;
  const int db = (bid >> 4) & 15;
  const int cb = bid & 15;
  const int d0 = db * 64, c0 = cb * 64;
  const float* src = w + (size_t)(kb + 1) * 1048576 + (size_t)d0 * 1024 + c0;
  #pragma unroll
  for (int p = 0; p < 4; ++p) {
    int dl = p * 16 + (t >> 4);
    int c4 = (t & 15) * 4;
    f32x4 f = *(const f32x4*)(src + (size_t)dl * 1024 + c4);
    unsigned lo = (unsigned)f2bf(f.x) | ((unsigned)f2bf(f.y) << 16);
    unsigned hi = (unsigned)f2bf(f.z) | ((unsigned)f2bf(f.w) << 16);
    ldsT[dl * 33 + (t & 15) * 2]     = lo;
    ldsT[dl * 33 + (t & 15) * 2 + 1] = hi;
  }
  __syncthreads();
  const int col = t >> 2;
  const int dc  = t & 3;
  union { unsigned short u[8]; s16x8 v; } o0, o1;
  #pragma unroll
  for (int j = 0; j < 16; ++j) {
    int dl = dc * 16 + j;
    unsigned word = ldsT[dl * 33 + (col >> 1)];
    unsigned short e = (col & 1) ? (unsigned short)(word >> 16) : (unsigned short)(word & 0xffffu);
    if (j < 8) o0.u[j] = e; else o1.u[j - 8] = e;
  }
  short* dst = wt + ((size_t)(kb * 1024 + c0 + col) * 1024 + d0 + dc * 16);
  *(s16x8*)dst       = o0.v;
  *(s16x8*)(dst + 8) = o1.v;
}

// ---------------- bias[c] = sum_d W[0][d][c] ----------------
__global__ __launch_bounds__(256) void bias_k(const float* __restrict__ w,
                                              float* __restrict__ b) {
  __shared__ float red[256];
  const int t = threadIdx.x;
  const int col = blockIdx.x * 64 + (t & 63);
  const int seg = t >> 6;
  float s = 0.f;
  const float* p = w + (size_t)(seg * 256) * 1024 + col;
  for (int d = 0; d < 256; ++d) s += p[(size_t)d * 1024];
  red[t] = s;
  __syncthreads();
  if (t < 64) b[col] = red[t] + red[t + 64] + red[t + 128] + red[t + 192];
}

// ---------------- out init: out[r][c] = bias[c] (or 0) ----------------
__global__ __launch_bounds__(256) void init_out(const float* __restrict__ bias,
                                                float* __restrict__ out, int has_bias) {
  const size_t i = (size_t)blockIdx.x * 256 + threadIdx.x;
  const int c = (int)((i * 4) & 1023);
  f32x4 v = has_bias ? *(const f32x4*)(bias + c) : (f32x4){0.f, 0.f, 0.f, 0.f};
  *(f32x4*)(out + i * 4) = v;
}

// ---------------- FULL path: m201-style fine-phase GEMM on materialized A ----------------
// BM=BN=256, split-K x2 (kb halves of 4096), grid 256 (1 block/CU), 512 thr,
// 8 waves (2wr x 4wc), wave 128x64, BK=32 (128 K-tiles).
// LDS 80 KB: A ring 3 x 16 KB @0, B ring 2 x 16 KB @49152.
// Per K-tile, 2 fine phases (m201 shape):
//   ph0: ds_read B(t) n0..3 + A(t) m0..3 || issue B(t+1) 2 gloads
//        -> barrier -> lgkm0 -> setprio1 -> 16 MFMA -> setprio0 -> barrier
//   ph1: ds_read A(t) m4..7              || issue A(t+2) 2 gloads
//        -> barrier -> lgkm0 -> setprio1 -> 16 MFMA -> setprio0
//        -> vmcnt(2)  [retires A(t+1),B(t+1); A(t+2) stays in flight] -> barrier
// vmcnt never 0 in the main loop (counted pipeline, T4). XCD-pinned (nb,kb):
// B panel 2 MB L2-resident. A re-read x4 across nb -> L3-served (R8: sustainable).
__global__ __launch_bounds__(512, 2) void gemm10(
    const short* __restrict__ amat, const short* __restrict__ wt2,
    float* __restrict__ out) {
  __shared__ __attribute__((aligned(16))) char lds[81920];

  const int tid = threadIdx.x, lane = tid & 63, wid = tid >> 6;
  const int bid = blockIdx.x;
  const int xcd = bid & 7;
  const int nb = xcd >> 1, kb = xcd & 1;    // one (nb,kb) per XCD
  const int mb = bid >> 3;                  // 0..31
  const int rowbase = mb * 256, colbase = nb * 256;
  const size_t kq = (size_t)kb * 4096;
  const int wr = wid >> 2, wc = wid & 3;    // wave tile 128M x 64N
  const int la = lane & 15, lg = lane >> 4;
  const int ela = (la & 3) ^ ((la >> 2) & 1);

  // fragment byte offsets (relative to operand ring base)
  int aoff[8], boff[4];
  #pragma unroll
  for (int m = 0; m < 8; ++m)
    aoff[m] = ((wr * 128 + m * 16 + la) << 6) + ((lg ^ ela) << 4);
  #pragma unroll
  for (int n = 0; n < 4; ++n)
    boff[n] = ((wc * 64 + n * 16 + la) << 6) + ((lg ^ ela) << 4);

  // staging: instr (wid,j) covers 16 rows (wid*32 + j*16 + rr), rr = lane>>2;
  // per-lane inverse-swizzled global 16B chunk
  const int rr   = lane >> 2;
  const int gchk = ((lane & 3) ^ ((rr & 3) ^ ((rr >> 2) & 1))) * 8;   // shorts
  const short* asrc = amat + (size_t)(rowbase + wid * 32 + rr) * 8192 + kq + gchk;
  const short* bsrc = wt2 + (size_t)(colbase + wid * 32 + rr) * 8192 + kq + gchk;
  const int sdst = wid * 2048 + (lane & 3) * 0;   // lane*16 added by HW; base per instr below

  f32x4 acc[8][4];
  #pragma unroll
  for (int m = 0; m < 8; ++m)
    #pragma unroll
    for (int n = 0; n < 4; ++n) acc[m][n] = (f32x4){0.f, 0.f, 0.f, 0.f};

#define STAGE_A(T, BUF)                                                            \
  { GLOAD_LDS16(asrc + (size_t)(T) * 32,              lds + (BUF) * 16384 + wid * 2048);        \
    GLOAD_LDS16(asrc + 16 * 8192 + (size_t)(T) * 32,  lds + (BUF) * 16384 + wid * 2048 + 1024); }
#define STAGE_B(T, BUF)                                                            \
  { GLOAD_LDS16(bsrc + (size_t)(T) * 32,              lds + 49152 + (BUF) * 16384 + wid * 2048);        \
    GLOAD_LDS16(bsrc + 16 * 8192 + (size_t)(T) * 32,  lds + 49152 + (BUF) * 16384 + wid * 2048 + 1024); }

  // prologue: A(0)->buf0, B(0)->buf0, A(1)->buf1; keep A(1) in flight
  STAGE_A(0, 0);
  STAGE_B(0, 0);
  STAGE_A(1, 1);
  WAITVM(2);
  __builtin_amdgcn_sched_barrier(0);
  __builtin_amdgcn_s_barrier();
  __builtin_amdgcn_sched_barrier(0);

  int ar = 0;        // A read buf = t % 3
  int aw = 2;        // A write buf = (t+2) % 3

  #pragma unroll 1
  for (int t = 0; t < 128; ++t) {
    const int ao = ar * 16384;
    const int bo = 49152 + (t & 1) * 16384;
    s16x8 bf[4], af[4];

    // ---- phase 0: m0..3 x n0..3 ----
    #pragma unroll
    for (int n = 0; n < 4; ++n) bf[n] = *(const s16x8*)(lds + bo + boff[n]);
    #pragma unroll
    for (int m = 0; m < 4; ++m) af[m] = *(const s16x8*)(lds + ao + aoff[m]);
    if (t < 127) STAGE_B(t + 1, (t + 1) & 1);
    __builtin_amdgcn_s_barrier();
    WAITLGKM0;
    __builtin_amdgcn_sched_barrier(0);
    __builtin_amdgcn_s_setprio(1);
    #pragma unroll
    for (int n = 0; n < 4; ++n)
      #pragma unroll
      for (int m = 0; m < 4; ++m)
        acc[m][n] = __builtin_amdgcn_mfma_f32_16x16x32_bf16(af[m], bf[n], acc[m][n], 0, 0, 0);
    __builtin_amdgcn_s_setprio(0);
    __builtin_amdgcn_sched_barrier(0);
    __builtin_amdgcn_s_barrier();
    __builtin_amdgcn_sched_barrier(0);

    // ---- phase 1: m4..7 x n0..3 (bf held in regs) ----
    #pragma unroll
    for (int m = 0; m < 4; ++m) af[m] = *(const s16x8*)(lds + ao + aoff[4 + m]);
    if (t < 126) STAGE_A(t + 2, aw);
    __builtin_amdgcn_s_barrier();
    WAITLGKM0;
    __builtin_amdgcn_sched_barrier(0);
    __builtin_amdgcn_s_setprio(1);
    #pragma unroll
    for (int n = 0; n < 4; ++n)
      #pragma unroll
      for (int m = 0; m < 4; ++m)
        acc[4 + m][n] = __builtin_amdgcn_mfma_f32_16x16x32_bf16(af[m], bf[n], acc[4 + m][n], 0, 0, 0);
    __builtin_amdgcn_s_setprio(0);
    // tile boundary: retire A(t+1),B(t+1); leave A(t+2) in flight (counted, never 0)
    if (t < 126) { WAITVM(2); } else { WAITVM(0); }
    __builtin_amdgcn_sched_barrier(0);
    __builtin_amdgcn_s_barrier();
    __builtin_amdgcn_sched_barrier(0);

    ar = (ar == 2) ? 0 : ar + 1;
    aw = (aw == 2) ? 0 : aw + 1;
  }
#undef STAGE_A
#undef STAGE_B

  // epilogue: out += acc (split-K x2 partial), hardware f32 atomics
  #pragma unroll
  for (int m = 0; m < 8; ++m) {
    const int r0 = rowbase + wr * 128 + m * 16 + lg * 4;
    #pragma unroll
    for (int n = 0; n < 4; ++n) {
      const int c = colbase + wc * 64 + n * 16 + la;
      #pragma unroll
      for (int j = 0; j < 4; ++j)
        unsafeAtomicAdd(&out[(size_t)(r0 + j) * 1024 + c], acc[m][n][j]);
    }
  }
}

// ---------------- MID path / fallback: R7 fused kernel (unchanged, proven) ----------------
template <bool USE_WS>
__global__ __launch_bounds__(256, 2) void cheb_gemm(
    const float* __restrict__ x, const float* __restrict__ w,
    const short* __restrict__ wt, float* __restrict__ out) {
  __shared__ short Asm[2][4096];
  __shared__ short Bsm[3][8192];

  const int tid = threadIdx.x, lane = tid & 63, wid = tid >> 6;
  const int bid = blockIdx.x;
  const int xcd = bid & 7;
  const int mb  = bid >> 3;
  const int nb  = xcd >> 1, kb = xcd & 1;
  const int rowbase = mb * 128, colbase = nb * 256;
  const int kbase = kb * 512;
  const int wr = wid >> 1, wc = wid & 1;
  const int la = lane & 15, lg = lane >> 4;
  const int e_la = (la & 3) ^ ((la >> 2) & 1);
  const int abase = (wr * 64 + la) * 64 + ((lg ^ e_la) << 4);
  const int bbase = (wc * 128 + la) * 64 + ((lg ^ e_la) << 4);

  const int arow = tid & 127, h = tid >> 7;
  const int aw0 = swz_byte(arow, 2 * h), aw1 = swz_byte(arow, 2 * h + 1);
  const float* xrow = x + (size_t)(rowbase + arow) * 1024 + kbase + h * 16;

  float p1[16], p2[16];
  unsigned x2h[8];
  f32x4 xq[4];
  f32x4 acc[4][8];
  #pragma unroll
  for (int m = 0; m < 4; ++m)
    #pragma unroll
    for (int n = 0; n < 8; ++n) acc[m][n] = (f32x4){0.f, 0.f, 0.f, 0.f};

  if constexpr (USE_WS) {
    const int bcol0  = wid * 64 + (lane >> 2);
    const int goff   = ((lane & 3) ^ swz_e(lane >> 2)) * 8;
    const short* gptr = wt + (size_t)(colbase + bcol0) * 1024 + kbase + goff;

#define ISSUE_AT(PTR, WOFF)                                                        \
    { _Pragma("unroll")                                                            \
      for (int j_ = 0; j_ < 4; ++j_)                                               \
        GLOAD_LDS16((PTR) + j_ * 16384,                                            \
                    (char*)&Bsm[0][0] + (WOFF) + (wid * 4 + j_) * 1024); }

    #pragma unroll
    for (int q = 0; q < 4; ++q) xq[q] = *(const f32x4*)(xrow + q * 4);
    ISSUE_AT(gptr, 0);          gptr += 1048576;
    ISSUE_AT(gptr, 16384);      gptr += 1048576;
    {
      union { unsigned short u[8]; s16x8 v; } o0, o1;
      #pragma unroll
      for (int i = 0; i < 16; ++i) { p1[i] = xq[i >> 2][i & 3]; p2[i] = 1.f; }
      #pragma unroll
      for (int i = 0; i < 8; ++i) {
        union { unsigned u; _Float16 f[2]; } t2;
        t2.f[0] = (_Float16)(p1[2 * i] + p1[2 * i]);
        t2.f[1] = (_Float16)(p1[2 * i + 1] + p1[2 * i + 1]);
        x2h[i] = t2.u;
        o0.u[i] = f2bf(p1[i]); o1.u[i] = f2bf(p1[i + 8]);
      }
      *(s16x8*)((char*)&Asm[0][0] + aw0) = o0.v;
      *(s16x8*)((char*)&Asm[0][0] + aw1) = o1.v;
    }
    WAITLGKM0;
    WAITVM(4);
    __builtin_amdgcn_sched_barrier(0);
    __builtin_amdgcn_s_barrier();
    __builtin_amdgcn_sched_barrier(0);

    int wroff = 32768, rdoff = 0, ard = 0;

    #pragma unroll 1
    for (int t = 0; t < 128; ++t) {
      if ((t & 7) == 2 && t < 120) {
        const float* xs = xrow + ((t >> 3) + 1) * 32;
        #pragma unroll
        for (int q = 0; q < 4; ++q) xq[q] = *(const f32x4*)(xs + q * 4);
      }
      if (t + 2 < 128) {
        ISSUE_AT(gptr, wroff);
        gptr += ((t & 7) == 5) ? (32 - 7 * 1048576) : 1048576;
        wroff = (wroff == 32768) ? 0 : wroff + 16384;
      }
      if (t + 1 < 128) {
        const int rn = (t + 1) & 7;
        union { unsigned short u[8]; s16x8 v; } o0, o1;
        if (rn == 0) {
          #pragma unroll
          for (int i = 0; i < 16; ++i) { p1[i] = xq[i >> 2][i & 3]; p2[i] = 1.f; }
          #pragma unroll
          for (int i = 0; i < 8; ++i) {
            union { unsigned u; _Float16 f[2]; } t2;
            t2.f[0] = (_Float16)(p1[2 * i] + p1[2 * i]);
            t2.f[1] = (_Float16)(p1[2 * i + 1] + p1[2 * i + 1]);
            x2h[i] = t2.u;
            o0.u[i] = f2bf(p1[i]); o1.u[i] = f2bf(p1[i + 8]);
          }
        } else {
          #pragma unroll
          for (int i = 0; i < 16; ++i) {
            union { unsigned u; _Float16 f[2]; } t2; t2.u = x2h[i >> 1];
            float cur = fmaf((float)t2.f[i & 1], p1[i], -p2[i]);
            p2[i] = p1[i]; p1[i] = cur;
            unsigned short e = f2bf(cur);
            if (i < 8) o0.u[i] = e; else o1.u[i - 8] = e;
          }
        }
        *(s16x8*)((char*)&Asm[0][0] + (ard ^ 8192) + aw0) = o0.v;
        *(s16x8*)((char*)&Asm[0][0] + (ard ^ 8192) + aw1) = o1.v;
      }
      s16x8 af[4];
      #pragma unroll
      for (int m = 0; m < 4; ++m)
        af[m] = *(const s16x8*)((char*)&Asm[0][0] + ard + abase + m * 1024);
      #pragma unroll
      for (int n = 0; n < 8; ++n) {
        s16x8 bfr = *(const s16x8*)((char*)&Bsm[0][0] + rdoff + bbase + n * 1024);
        #pragma unroll
        for (int m = 0; m < 4; ++m)
          acc[m][n] = __builtin_amdgcn_mfma_f32_16x16x32_bf16(af[m], bfr, acc[m][n], 0, 0, 0);
      }
      WAITLGKM0;
      if (t < 126) { WAITVM(4); } else { WAITVM(0); }
      __builtin_amdgcn_sched_barrier(0);
      __builtin_amdgcn_s_barrier();
      __builtin_amdgcn_sched_barrier(0);
      rdoff = (rdoff == 32768) ? 0 : rdoff + 16384;
      ard ^= 8192;
    }
#undef ISSUE_AT
  } else {
    #pragma unroll 1
    for (int s = 0; s < 144; ++s) {
      const int r = s % 9, st = s / 9;
      const int d0 = kbase + st * 32;
      __syncthreads();
      { const int dd = tid & 31, cg = tid >> 5;
        const float* ws_ = w + (size_t)r * 1048576 + (size_t)(d0 + dd) * 1024 + colbase + cg * 4;
        #pragma unroll
        for (int p_ = 0; p_ < 8; ++p_) {
          f32x4 f_ = *(const f32x4*)(ws_ + p_ * 32);
          #pragma unroll
          for (int jj = 0; jj < 4; ++jj) {
            int col = cg * 4 + p_ * 32 + jj;
            int byt = col * 64 + ((dd & 7) << 1) + ((((dd >> 3) ^ swz_e(col)) & 3) << 4);
            *(unsigned short*)((char*)&Bsm[0][0] + byt) = f2bf(f_[jj]);
          } } }
      union { unsigned short u[8]; s16x8 v; } o0, o1;
      if (r == 0) {
        #pragma unroll
        for (int q = 0; q < 4; ++q) xq[q] = *(const f32x4*)(xrow + st * 32 + q * 4);
        #pragma unroll
        for (int i = 0; i < 16; ++i) { p1[i] = xq[i >> 2][i & 3]; p2[i] = 1.f; }
        #pragma unroll
        for (int i = 0; i < 8; ++i) {
          union { unsigned u; _Float16 f[2]; } t2;
          t2.f[0] = (_Float16)(p1[2 * i] + p1[2 * i]);
          t2.f[1] = (_Float16)(p1[2 * i + 1] + p1[2 * i + 1]);
          x2h[i] = t2.u;
          o0.u[i] = 0x3f80; o1.u[i] = 0x3f80;
        }
      } else if (r == 1) {
        #pragma unroll
        for (int i = 0; i < 8; ++i) { o0.u[i] = f2bf(p1[i]); o1.u[i] = f2bf(p1[i + 8]); }
      } else {
        #pragma unroll
        for (int i = 0; i < 16; ++i) {
          union { unsigned u; _Float16 f[2]; } t2; t2.u = x2h[i >> 1];
          float cur = fmaf((float)t2.f[i & 1], p1[i], -p2[i]);
          p2[i] = p1[i]; p1[i] = cur;
          if (i < 8) o0.u[i] = f2bf(cur); else o1.u[i - 8] = f2bf(cur);
        }
      }
      *(s16x8*)((char*)&Asm[0][0] + aw0) = o0.v;
      *(s16x8*)((char*)&Asm[0][0] + aw1) = o1.v;
      __syncthreads();
      s16x8 af[4];
      #pragma unroll
      for (int m = 0; m < 4; ++m)
        af[m] = *(const s16x8*)((char*)&Asm[0][0] + abase + m * 1024);
      #pragma unroll
      for (int n = 0; n < 8; ++n) {
        s16x8 bfr = *(const s16x8*)((char*)&Bsm[0][0] + bbase + n * 1024);
        #pragma unroll
        for (int m = 0; m < 4; ++m)
          acc[m][n] = __builtin_amdgcn_mfma_f32_16x16x32_bf16(af[m], bfr, acc[m][n], 0, 0, 0);
      }
    }
  }

  #pragma unroll
  for (int m = 0; m < 4; ++m) {
    const int r0 = rowbase + wr * 64 + m * 16 + lg * 4;
    #pragma unroll
    for (int n = 0; n < 8; ++n) {
      const int c = colbase + wc * 128 + n * 16 + la;
      #pragma unroll
      for (int j = 0; j < 4; ++j)
        unsafeAtomicAdd(&out[(size_t)(r0 + j) * 1024 + c], acc[m][n][j]);
    }
  }
}

extern "C" void kernel_launch(void* const* d_in, const int* in_sizes, int n_in,
                              void* d_out, int out_size, void* d_ws, size_t ws_size,
                              hipStream_t stream) {
  const float* x = (const float*)d_in[0];
  const float* w = (const float*)d_in[1];
  float* out = (float*)d_out;

  const size_t AMAT_BYTES = (size_t)8192 * 8192 * 2;   // 134 MiB
  const size_t WT2_BYTES  = (size_t)1024 * 8192 * 2;   // 16 MiB
  const size_t WT_BYTES   = (size_t)8 * 1024 * 1024 * 2;

  if (ws_size >= AMAT_BYTES + WT2_BYTES + 4096) {
    // FULL: materialize A, re-layout W, m201-style fine-phase GEMM
    short* amat = (short*)d_ws;
    short* wt2  = (short*)((char*)d_ws + AMAT_BYTES);
    float* bias = (float*)((char*)d_ws + AMAT_BYTES + WT2_BYTES);
    agen<<<4096, 256, 0, stream>>>(x, amat);
    transpose_w2<<<2048, 256, 0, stream>>>(w, wt2);
    bias_k<<<16, 256, 0, stream>>>(w, bias);
    init_out<<<8192, 256, 0, stream>>>(bias, out, 1);
    gemm10<<<256, 512, 0, stream>>>(amat, wt2, out);
  } else if (ws_size >= WT_BYTES + 4096) {
    // MID: R7 fused kernel
    short* wt   = (short*)d_ws;
    float* bias = (float*)((char*)d_ws + WT_BYTES);
    transpose_w<<<2048, 256, 0, stream>>>(w, wt);
    bias_k<<<16, 256, 0, stream>>>(w, bias);
    init_out<<<8192, 256, 0, stream>>>(bias, out, 1);
    cheb_gemm<true><<<512, 256, 0, stream>>>(x, w, wt, out);
  } else {
    init_out<<<8192, 256, 0, stream>>>(nullptr, out, 0);
    cheb_gemm<false><<<512, 256, 0, stream>>>(x, w, nullptr, out);
  }
}